// Round 1
// baseline (452.232 us; speedup 1.0000x reference)
//
#include <hip/hip_runtime.h>
#include <hip/hip_bf16.h>
#include <math.h>

// ---- problem constants ----
#define NB 256      // batch
#define NN 307      // vertices
#define LL 12       // sequence length
#define DDIM 16     // model dim
#define HISW 268    // 267 history cols + 1 zero pad (for float4)
#define HIS4 67     // HISW/4
#define NBRCAP 128  // per-row neighbor capacity (p=0.03 -> mean 9.2; 128 is unreachable)

// ---- workspace layout (float offsets; every segment 16B-aligned) ----
#define OFF_XTCN 0u            // 15089664 floats  [B,N,L,D]
#define OFF_G1   15089664u     //   943104 floats  [B,N,L]
#define OFF_ADT  16032768u     //    94249 floats  A_dyn^T [m][n] (pad to 94256)
#define OFF_TE   16127024u     //    49152 floats  [B,L,D] = pe + day_emb + week_emb
#define OFF_HIS  16176176u     //    82276 floats  [N,268] (pad to 82288)
#define OFF_NW   16258464u     //    39296 floats  nbr weights [N,128]
#define OFF_NIDX 16297760u     //    39296 ints    nbr indices [N,128]
#define OFF_NCNT 16337056u     //      307 ints    nbr counts

__device__ inline float4 mkf4(float a, float b, float c, float d) {
    float4 r; r.x = a; r.y = b; r.z = c; r.w = d; return r;
}

// ---------------------------------------------------------------------------
// K0a: build padded history matrix his[N][268]
// his[n, j<12] = flow[0,n,j]; his[n, 12<=j<267] = flow[j-11, n, 11]; his[n,267]=0
// ---------------------------------------------------------------------------
__global__ void his_kernel(const float* __restrict__ flow, float* __restrict__ his) {
    int e = blockIdx.x * 256 + threadIdx.x;
    if (e >= NN * HISW) return;
    int n = e / HISW, j = e - n * HISW;
    float v = 0.f;
    if (j < LL) v = flow[n * LL + j];                       // b=0 block
    else if (j < 267) v = flow[((j - 11) * NN + n) * LL + 11];
    his[e] = v;
}

// ---------------------------------------------------------------------------
// K0b: TE[b,l,d] = pos_enc(l,d) + day_emb[day_cyc[b,l],d] + week_emb[week_cyc[b,l],d]
// ---------------------------------------------------------------------------
__global__ void te_kernel(const int* __restrict__ dayc, const int* __restrict__ weekc,
                          const float* __restrict__ demb, const float* __restrict__ wemb,
                          float* __restrict__ TE) {
    int e = blockIdx.x * 256 + threadIdx.x;
    if (e >= NB * LL * DDIM) return;
    int d = e & 15, l = (e >> 4) % LL, b = e / (LL * DDIM);
    int dc = dayc[b * LL + l], wc = weekc[b * LL + l];
    int i = d >> 1;
    float ang = (float)l * powf(10000.f, -0.125f * (float)i);
    float pe = (d & 1) ? cosf(ang) : sinf(ang);
    TE[e] = demb[dc * DDIM + d] + wemb[wc * DDIM + d] + pe;
}

// ---------------------------------------------------------------------------
// K1: A_dyn (row-softmax of -euclid_dist) stored TRANSPOSED: AdT[m*307+n]
// One block per row n; dist^2 computed as sum((a-b)^2) (exact 0 on diagonal,
// so implicit softmax max-shift of 0 is exact).
// ---------------------------------------------------------------------------
__global__ __launch_bounds__(256) void adyn_kernel(const float* __restrict__ his,
                                                   float* __restrict__ AdT) {
    __shared__ float4 sh[HIS4];
    __shared__ float red[256];
    int n = blockIdx.x, t = threadIdx.x;
    if (t < HIS4) sh[t] = reinterpret_cast<const float4*>(his)[n * HIS4 + t];
    __syncthreads();

    float e0 = 0.f, e1 = 0.f, lsum = 0.f;
    {
        const float4* row = reinterpret_cast<const float4*>(his) + t * HIS4;
        float4 acc = mkf4(0.f, 0.f, 0.f, 0.f);
        for (int j = 0; j < HIS4; j++) {
            float4 a = sh[j], b = row[j];
            float dx = a.x - b.x, dy = a.y - b.y, dz = a.z - b.z, dw = a.w - b.w;
            acc.x += dx * dx; acc.y += dy * dy; acc.z += dz * dz; acc.w += dw * dw;
        }
        float d2 = (acc.x + acc.y) + (acc.z + acc.w);
        e0 = __expf(-sqrtf(fmaxf(d2, 0.f)));
        lsum += e0;
    }
    int m1 = t + 256;
    if (m1 < NN) {
        const float4* row = reinterpret_cast<const float4*>(his) + m1 * HIS4;
        float4 acc = mkf4(0.f, 0.f, 0.f, 0.f);
        for (int j = 0; j < HIS4; j++) {
            float4 a = sh[j], b = row[j];
            float dx = a.x - b.x, dy = a.y - b.y, dz = a.z - b.z, dw = a.w - b.w;
            acc.x += dx * dx; acc.y += dy * dy; acc.z += dz * dz; acc.w += dw * dw;
        }
        float d2 = (acc.x + acc.y) + (acc.z + acc.w);
        e1 = __expf(-sqrtf(fmaxf(d2, 0.f)));
        lsum += e1;
    }
    red[t] = lsum;
    __syncthreads();
    for (int s = 128; s > 0; s >>= 1) {
        if (t < s) red[t] += red[t + s];
        __syncthreads();
    }
    float inv = 1.f / red[0];
    AdT[t * NN + n] = e0 * inv;
    if (m1 < NN) AdT[m1 * NN + n] = e1 * inv;
}

// ---------------------------------------------------------------------------
// K2: sparse A_st rows: w = adj[n,m]/(rowsum+1) for adj!=0, compacted per row.
// One wave per row; ballot-compaction.
// ---------------------------------------------------------------------------
__global__ __launch_bounds__(64) void nbr_kernel(const float* __restrict__ adj,
                                                 int* __restrict__ ncnt,
                                                 int* __restrict__ nidx,
                                                 float* __restrict__ nw) {
    int n = blockIdx.x, t = threadIdx.x;
    float rs = 0.f;
    for (int m0 = 0; m0 < NN; m0 += 64) {
        int m = m0 + t;
        if (m < NN) rs += adj[n * NN + m];
    }
    for (int off = 32; off > 0; off >>= 1) rs += __shfl_xor(rs, off);
    float inv = 1.f / (rs + 1.f);
    int c = 0;
    for (int m0 = 0; m0 < NN; m0 += 64) {
        int m = m0 + t;
        float a = (m < NN) ? adj[n * NN + m] : 0.f;
        bool p = (a != 0.f);
        unsigned long long mask = __ballot(p);
        int pos = __popcll(mask & ((1ull << t) - 1ull));
        if (p && (c + pos) < NBRCAP) {
            nidx[n * NBRCAP + c + pos] = m;
            nw[n * NBRCAP + c + pos] = a * inv;
        }
        c += (int)__popcll(mask);
    }
    if (t == 0) ncnt[n] = c < NBRCAP ? c : NBRCAP;
}

// ---------------------------------------------------------------------------
// K3: fused per-(b,n) temporal self-attention -> x_tcn[b,n,l,d]
// One 64-lane wave per (b,n). All tiles in LDS, float4-vectorized.
// ---------------------------------------------------------------------------
__device__ inline void attn_row(int l, int h, const float2* q2, const float2* kk,
                                const float2* vv, float2* a2) {
    float2 q = q2[l * 8 + h];
    float s[LL];
    float mx = -1e30f;
#pragma unroll
    for (int m = 0; m < LL; m++) {
        s[m] = (q.x * kk[m].x + q.y * kk[m].y) * 0.70710678118654752f;
        mx = fmaxf(mx, s[m]);
    }
    float sum = 0.f;
#pragma unroll
    for (int m = 0; m < LL; m++) { s[m] = __expf(s[m] - mx); sum += s[m]; }
    float inv = 1.f / sum;
    float a0 = 0.f, a1 = 0.f;
#pragma unroll
    for (int m = 0; m < LL; m++) { a0 += s[m] * vv[m].x; a1 += s[m] * vv[m].y; }
    float2 r; r.x = a0 * inv; r.y = a1 * inv;
    a2[l * 8 + h] = r;
}

__global__ __launch_bounds__(64) void attn_kernel(
    const float* __restrict__ flow, const float* __restrict__ TE,
    const float* __restrict__ Wq, const float* __restrict__ bq,
    const float* __restrict__ Wk, const float* __restrict__ bk,
    const float* __restrict__ Wv, const float* __restrict__ bv,
    const float* __restrict__ Wo, const float* __restrict__ bo,
    float* __restrict__ xtcn) {
    __shared__ float4 sXT[48], sQ[48], sK[48], sV[48], sATT[48];
    const int t = threadIdx.x;
    const int bn = blockIdx.x;
    const int b = bn / NN, n = bn - b * NN;

    // stage 1: x_t = flow + TE (TE already includes pos-enc)
    if (t < 48) {
        int l = t >> 2, j = t & 3;
        float f = flow[(b * NN + n) * LL + l];
        float4 te = reinterpret_cast<const float4*>(TE)[(b * LL + l) * 4 + j];
        sXT[t] = mkf4(f + te.x, f + te.y, f + te.z, f + te.w);
    }
    __syncthreads();

    // stage 2: q,k,v = x_t @ W + b   (144 float4 chunks over 64 lanes)
    const float4* Wq4 = reinterpret_cast<const float4*>(Wq);
    const float4* Wk4 = reinterpret_cast<const float4*>(Wk);
    const float4* Wv4 = reinterpret_cast<const float4*>(Wv);
    const float4* bq4 = reinterpret_cast<const float4*>(bq);
    const float4* bk4 = reinterpret_cast<const float4*>(bk);
    const float4* bv4 = reinterpret_cast<const float4*>(bv);
#pragma unroll
    for (int kk_ = 0; kk_ < 3; kk_++) {
        int id = t + kk_ * 64;
        if (id < 144) {
            int mat = id / 48;
            int wi = id - mat * 48;
            int l = wi >> 2, j = wi & 3;
            const float4* W4 = (mat == 0) ? Wq4 : ((mat == 1) ? Wk4 : Wv4);
            const float4* B4 = (mat == 0) ? bq4 : ((mat == 1) ? bk4 : bv4);
            float4 acc = B4[j];
            float4 x0 = sXT[l * 4 + 0], x1 = sXT[l * 4 + 1];
            float4 x2 = sXT[l * 4 + 2], x3 = sXT[l * 4 + 3];
            float xe[16] = {x0.x, x0.y, x0.z, x0.w, x1.x, x1.y, x1.z, x1.w,
                            x2.x, x2.y, x2.z, x2.w, x3.x, x3.y, x3.z, x3.w};
#pragma unroll
            for (int e = 0; e < 16; e++) {
                float4 wv = W4[e * 4 + j];
                acc.x += xe[e] * wv.x; acc.y += xe[e] * wv.y;
                acc.z += xe[e] * wv.z; acc.w += xe[e] * wv.w;
            }
            float4* dst = (mat == 0) ? sQ : ((mat == 1) ? sK : sV);
            dst[wi] = acc;
        }
    }
    __syncthreads();

    // stage 3: per-(h,l) softmax row + P@V. lane t -> (l=t>>3, h=t&7); lanes<32
    // also do (l=8+(t>>3), same h) so k/v column loads are shared.
    {
        const float2* q2 = reinterpret_cast<const float2*>(sQ);
        const float2* k2 = reinterpret_cast<const float2*>(sK);
        const float2* v2 = reinterpret_cast<const float2*>(sV);
        float2* a2 = reinterpret_cast<float2*>(sATT);
        int h = t & 7, l1 = t >> 3;
        float2 kk[LL], vv[LL];
#pragma unroll
        for (int m = 0; m < LL; m++) { kk[m] = k2[m * 8 + h]; vv[m] = v2[m * 8 + h]; }
        attn_row(l1, h, q2, kk, vv, a2);
        if (t < 32) attn_row(8 + (t >> 3), h, q2, kk, vv, a2);
    }
    __syncthreads();

    // stage 4: x_tcn = x_t + att @ Wo + bo  -> global (coalesced float4)
    if (t < 48) {
        int l = t >> 2, j = t & 3;
        float4 acc = reinterpret_cast<const float4*>(bo)[j];
        float4 a0 = sATT[l * 4 + 0], a1 = sATT[l * 4 + 1];
        float4 a2_ = sATT[l * 4 + 2], a3 = sATT[l * 4 + 3];
        float ae[16] = {a0.x, a0.y, a0.z, a0.w, a1.x, a1.y, a1.z, a1.w,
                        a2_.x, a2_.y, a2_.z, a2_.w, a3.x, a3.y, a3.z, a3.w};
#pragma unroll
        for (int e = 0; e < 16; e++) {
            float4 wv = reinterpret_cast<const float4*>(Wo)[e * 4 + j];
            acc.x += ae[e] * wv.x; acc.y += ae[e] * wv.y;
            acc.z += ae[e] * wv.z; acc.w += ae[e] * wv.w;
        }
        float4 xt = sXT[t];
        reinterpret_cast<float4*>(xtcn)[(size_t)bn * 48 + t] =
            mkf4(xt.x + acc.x, xt.y + acc.y, xt.z + acc.z, xt.w + acc.w);
    }
}

// ---------------------------------------------------------------------------
// K4: G1[b,n,l] = sum_m A_dyn[n,m] * flow[b,m,l]  (A_dyn stored transposed ->
// coalesced over n; flow row is wave-uniform -> scalar loads)
// ---------------------------------------------------------------------------
__global__ __launch_bounds__(320) void g1_kernel(const float* __restrict__ flow,
                                                 const float* __restrict__ AdT,
                                                 float* __restrict__ G1) {
    int b = blockIdx.x, n = threadIdx.x;
    if (n >= NN) return;
    const float* fb = flow + (size_t)b * NN * LL;
    float acc[LL];
#pragma unroll
    for (int l = 0; l < LL; l++) acc[l] = 0.f;
    for (int m = 0; m < NN; m++) {
        float w = AdT[m * NN + n];
        float fr[LL];
#pragma unroll
        for (int l = 0; l < LL; l++) fr[l] = fb[m * LL + l];
#pragma unroll
        for (int l = 0; l < LL; l++) acc[l] += w * fr[l];
    }
    float* dst = G1 + ((size_t)b * NN + n) * LL;
#pragma unroll
    for (int l = 0; l < LL; l++) dst[l] = acc[l];
}

// ---------------------------------------------------------------------------
// K5: fused graph-mix + MLP head. One wave per (b,n):
//   y[l,d]  = sum_nbr w * x_tcn[b,m,l,d]                 (sparse A_st gather)
//   hid     = relu(G1*Wg + y@Wt + bg)    [12,32]
//   h1      = relu(hid @ W1[n] + b1[n])  [12,8]
//   out     = h1 @ W2[n] + b2[n]         [12]
// ---------------------------------------------------------------------------
__global__ __launch_bounds__(64) void final_kernel(
    const float* __restrict__ xtcn, const float* __restrict__ G1,
    const float* __restrict__ Wg, const float* __restrict__ Wt,
    const float* __restrict__ bg, const float* __restrict__ W1,
    const float* __restrict__ b1, const float* __restrict__ W2,
    const float* __restrict__ b2, const int* __restrict__ ncnt,
    const int* __restrict__ nidx, const float* __restrict__ nw,
    float* __restrict__ out) {
    __shared__ float sY[192];
    __shared__ float4 sHID[96];   // [l][8] float4 = [l][32] floats
    __shared__ float sH1[96];     // [l][8]
    int t = threadIdx.x, bn = blockIdx.x;
    int b = bn / NN, n = bn - b * NN;

    // sparse aggregation (indices/weights wave-uniform -> scalar loads)
    int cnt = ncnt[n];
    float y0 = 0.f, y1 = 0.f, y2 = 0.f;
    const float* base = xtcn + (size_t)b * NN * 192;
    for (int i = 0; i < cnt; i++) {
        int m = nidx[n * NBRCAP + i];
        float w = nw[n * NBRCAP + i];
        const float* src = base + m * 192;
        y0 += w * src[t]; y1 += w * src[t + 64]; y2 += w * src[t + 128];
    }
    sY[t] = y0; sY[t + 64] = y1; sY[t + 128] = y2;
    __syncthreads();

    // hid = relu(G1*Wg + y@Wt + bg): 96 float4 chunks (c -> l=c>>3, j=c&7)
#pragma unroll
    for (int p = 0; p < 2; p++) {
        int c = t + p * 64;
        if (c < 96) {
            int l = c >> 3, j = c & 7;
            float g = G1[(size_t)bn * LL + l];
            float4 wg = reinterpret_cast<const float4*>(Wg)[j];
            float4 acc = reinterpret_cast<const float4*>(bg)[j];
            acc.x += g * wg.x; acc.y += g * wg.y; acc.z += g * wg.z; acc.w += g * wg.w;
            const float4* yr = reinterpret_cast<const float4*>(sY) + l * 4;
            float4 v0 = yr[0], v1 = yr[1], v2 = yr[2], v3 = yr[3];
            float ye[16] = {v0.x, v0.y, v0.z, v0.w, v1.x, v1.y, v1.z, v1.w,
                            v2.x, v2.y, v2.z, v2.w, v3.x, v3.y, v3.z, v3.w};
#pragma unroll
            for (int d = 0; d < 16; d++) {
                float4 wt = reinterpret_cast<const float4*>(Wt)[d * 8 + j];
                acc.x += ye[d] * wt.x; acc.y += ye[d] * wt.y;
                acc.z += ye[d] * wt.z; acc.w += ye[d] * wt.w;
            }
            acc.x = fmaxf(acc.x, 0.f); acc.y = fmaxf(acc.y, 0.f);
            acc.z = fmaxf(acc.z, 0.f); acc.w = fmaxf(acc.w, 0.f);
            sHID[c] = acc;
        }
    }
    __syncthreads();

    // h1 = relu(hid @ W1[n] + b1[n]): 96 outputs (o -> l=o>>3, oo=o&7)
#pragma unroll
    for (int p = 0; p < 2; p++) {
        int o = t + p * 64;
        if (o < 96) {
            int l = o >> 3, oo = o & 7;
            float acc = b1[n * 8 + oo];
            float he[32];
#pragma unroll
            for (int k = 0; k < 8; k++) {
                float4 hv = sHID[l * 8 + k];
                he[4 * k + 0] = hv.x; he[4 * k + 1] = hv.y;
                he[4 * k + 2] = hv.z; he[4 * k + 3] = hv.w;
            }
#pragma unroll
            for (int c = 0; c < 32; c++) acc += he[c] * W1[(n * 32 + c) * 8 + oo];
            sH1[o] = fmaxf(acc, 0.f);
        }
    }
    __syncthreads();

    // out = h1 @ W2[n] + b2[n]
    if (t < LL) {
        float acc = b2[n];
#pragma unroll
        for (int o = 0; o < 8; o++) acc += sH1[t * 8 + o] * W2[n * 8 + o];
        out[(size_t)bn * LL + t] = acc;
    }
}

// ---------------------------------------------------------------------------
extern "C" void kernel_launch(void* const* d_in, const int* in_sizes, int n_in,
                              void* d_out, int out_size, void* d_ws, size_t ws_size,
                              hipStream_t stream) {
    const float* flow = (const float*)d_in[0];
    const int* dayc   = (const int*)d_in[1];
    const int* weekc  = (const int*)d_in[2];
    const float* adj  = (const float*)d_in[3];
    const float* demb = (const float*)d_in[4];
    const float* wemb = (const float*)d_in[5];
    const float* Wq = (const float*)d_in[6];  const float* bq = (const float*)d_in[7];
    const float* Wk = (const float*)d_in[8];  const float* bk = (const float*)d_in[9];
    const float* Wv = (const float*)d_in[10]; const float* bv = (const float*)d_in[11];
    const float* Wo = (const float*)d_in[12]; const float* bo = (const float*)d_in[13];
    const float* Wg = (const float*)d_in[14]; const float* Wt = (const float*)d_in[15];
    const float* bg = (const float*)d_in[16];
    const float* W1 = (const float*)d_in[17]; const float* b1 = (const float*)d_in[18];
    const float* W2 = (const float*)d_in[19]; const float* b2 = (const float*)d_in[20];
    float* out = (float*)d_out;
    float* ws  = (float*)d_ws;

    float* xtcn = ws + OFF_XTCN;
    float* G1   = ws + OFF_G1;
    float* AdT  = ws + OFF_ADT;
    float* TE   = ws + OFF_TE;
    float* his  = ws + OFF_HIS;
    float* nw   = ws + OFF_NW;
    int*   nidx = (int*)(ws + OFF_NIDX);
    int*   ncnt = (int*)(ws + OFF_NCNT);

    his_kernel<<<(NN * HISW + 255) / 256, 256, 0, stream>>>(flow, his);
    te_kernel<<<(NB * LL * DDIM + 255) / 256, 256, 0, stream>>>(dayc, weekc, demb, wemb, TE);
    adyn_kernel<<<NN, 256, 0, stream>>>(his, AdT);
    nbr_kernel<<<NN, 64, 0, stream>>>(adj, ncnt, nidx, nw);
    attn_kernel<<<NB * NN, 64, 0, stream>>>(flow, TE, Wq, bq, Wk, bk, Wv, bv, Wo, bo, xtcn);
    g1_kernel<<<NB, 320, 0, stream>>>(flow, AdT, G1);
    final_kernel<<<NB * NN, 64, 0, stream>>>(xtcn, G1, Wg, Wt, bg, W1, b1, W2, b2,
                                             ncnt, nidx, nw, out);
}